// Round 1
// 2047.303 us; speedup vs baseline: 1.0625x; 1.0625x over previous
//
#include <hip/hip_runtime.h>
#include <hip/hip_bf16.h>

// B=64, S=512, I=256, H=512 LSTM forward.
// R6: B-operands in registers. Occupancy is 1 wave/SIMD (LDS-bound), so each
// wave owns the full 512-VGPR unified file; the step-invariant U-slice
// (128 VGPRs/wave) and W-slice (64 VGPRs/wave) move from LDS/global into
// VGPRs once at startup. Steady-state h@U becomes 16x{1 ds_read_b128 + 2 MFMA}
// (was 48 ds_read_b128/wave/step), cutting ~1600+ cycles of LDS-pipe wall time
// off the per-step serial chain and killing the Ut bank-conflict pattern.
// Communication scheme unchanged from R5: batch-group decomposition, 4 groups
// x 16 WGs, h published as self-certifying u64 atoms (tag<<32 | 2xbf16) via
// relaxed agent-scope stores; consumers bulk-issue 16 coalesced atomic loads
// and do ONE combined tag check. The spin IS the group barrier.

#define BB 64
#define SS 512
#define II 256
#define HH 512
#define G4 2048
#define NGRP 4     // batch groups
#define GB 16      // batches per group
#define NWPG 16    // WGs per group
#define NCOL 128   // gate cols per WG = 4 gates x 32 units
#define NU 32      // hidden units per WG

typedef __attribute__((ext_vector_type(8))) short bf16x8;
typedef __attribute__((ext_vector_type(4))) float f32x4;
typedef unsigned long long u64t;

__device__ __forceinline__ u64t ld_llc_u64(const u64t* p) {
  return __hip_atomic_load((u64t*)p, __ATOMIC_RELAXED,
                           __HIP_MEMORY_SCOPE_AGENT);
}
__device__ __forceinline__ void st_llc_u64(u64t* p, u64t v) {
  __hip_atomic_store(p, v, __ATOMIC_RELAXED, __HIP_MEMORY_SCOPE_AGENT);
}

// x [b][t][i] fp32 -> xb [t][b][i] bf16
__global__ void convert_x_kernel(const float* __restrict__ x,
                                 __hip_bfloat16* __restrict__ xb) {
  int blk = blockIdx.x;          // b*SS + t
  int b = blk >> 9;
  int t = blk & (SS - 1);
  int i = threadIdx.x;
  xb[((size_t)t * BB + b) * II + i] = __float2bfloat16(x[(size_t)blk * II + i]);
}

// W [256][2048] fp32 -> Wt [2048][256] bf16 (row = gate col, for B-frags)
__global__ void transpose_w_kernel(const float* __restrict__ W,
                                   __hip_bfloat16* __restrict__ Wt) {
  __shared__ __hip_bfloat16 tile[64][64 + 8];
  int kb = blockIdx.x & 3;       // 4 k-blocks
  int nb = blockIdx.x >> 2;      // 32 n-blocks
  int k0 = kb * 64, nb0 = nb * 64;
#pragma unroll
  for (int p = 0; p < 16; ++p) {
    int r = p * 4 + (threadIdx.x >> 6);
    int c = threadIdx.x & 63;
    tile[r][c] = __float2bfloat16(W[(size_t)(k0 + r) * G4 + nb0 + c]);
  }
  __syncthreads();
#pragma unroll
  for (int p = 0; p < 16; ++p) {
    int n = p * 4 + (threadIdx.x >> 6);
    int k = threadIdx.x & 63;
    Wt[(size_t)(nb0 + n) * II + k0 + k] = tile[k][n];
  }
}

__global__ __launch_bounds__(256, 1)
void lstm_step(const float* __restrict__ U,
               const float* __restrict__ bias,
               const __hip_bfloat16* __restrict__ xb,
               const __hip_bfloat16* __restrict__ Wt,
               u64t* __restrict__ hpub,   // [NGRP][2][GB*256] u64
               float* __restrict__ out) {
  // LDS: Ut 133.1K (staging only) + hL 16.6K + gate 8.4K + bias 0.5K = 158.7K
  __shared__ alignas(16) __hip_bfloat16 Ut[NCOL][HH + 8];
  __shared__ alignas(16) __hip_bfloat16 hL[GB][HH + 8];
  __shared__ float gate[GB][NCOL + 4];
  __shared__ float bia[NCOL];

  const int tid = threadIdx.x;
  const int wgid = blockIdx.x;
  const int grp = wgid >> 4;     // batch group 0..3
  const int w16 = wgid & 15;     // WG within group
  const int n0 = w16 * NU;       // hidden-unit offset of this WG's slice

  // ---- one-time: stage U column-slice (transposed, bf16) + bias ----
  // local col c = g*32 + j  <->  global col g*512 + n0 + j
  for (int i = tid; i < NCOL * HH; i += 256) {
    int c = i & (NCOL - 1);
    int k = i >> 7;
    int g = c >> 5, j = c & 31;
    Ut[c][k] = __float2bfloat16(U[(size_t)k * G4 + g * HH + n0 + j]);
  }
  if (tid < NCOL) {
    int g = tid >> 5, j = tid & 31;
    bia[tid] = bias[g * HH + n0 + j];
  }
  __syncthreads();

  const int lane = tid & 63;
  const int wave = tid >> 6;
  const int l16 = lane & 15;
  const int quad = lane >> 4;
  const int c0i = (2 * wave) * 16 + l16;       // this lane's col, n-tile 0
  const int c1i = (2 * wave + 1) * 16 + l16;   // this lane's col, n-tile 1

  // ---- one-time: hoist step-invariant B-operands into VGPRs ----
  // U-frags: 2 tiles x 16 ks x 4 VGPR = 128 VGPRs/lane.
  bf16x8 uf0[16], uf1[16];
#pragma unroll
  for (int ks = 0; ks < 16; ++ks) {
    uf0[ks] = *(const bf16x8*)(&Ut[c0i][ks * 32 + quad * 8]);
    uf1[ks] = *(const bf16x8*)(&Ut[c1i][ks * 32 + quad * 8]);
  }
  // W-frags: 2 tiles x 8 ks x 4 VGPR = 64 VGPRs/lane.
  // B-frag row in Wt (global col = (c>>5)*512 + n0 + (c&31))
  const __hip_bfloat16* wrow0 =
      Wt + (size_t)((c0i >> 5) * HH + n0 + (c0i & 31)) * II;
  const __hip_bfloat16* wrow1 =
      Wt + (size_t)((c1i >> 5) * HH + n0 + (c1i & 31)) * II;
  bf16x8 wf0[8], wf1[8];
#pragma unroll
  for (int ks = 0; ks < 8; ++ks) {
    wf0[ks] = *(const bf16x8*)(wrow0 + ks * 32 + quad * 8);
    wf1[ks] = *(const bf16x8*)(wrow1 + ks * 32 + quad * 8);
  }
  // bias for this lane's two columns (step-invariant)
  const float b0 = bia[c0i];
  const float b1 = bia[c1i];

  // eltwise ownership: thread -> cells (eb, ej) and (eb, ej+1)
  const int eb = (2 * tid) >> 5;   // batch-local 0..15
  const int ej = (2 * tid) & 31;   // even unit index 0..30
  float cs0 = 0.f, cs1 = 0.f;

  u64t* gbase = hpub + (size_t)grp * 2 * (GB * 256);

  for (int t = 0; t < SS; ++t) {
    const u64t* hr = gbase + (size_t)((t & 1) ^ 1) * (GB * 256);
    u64t* hw = gbase + (size_t)(t & 1) * (GB * 256);
    const unsigned ewant = (unsigned)t;
    const unsigned epub = (unsigned)(t + 1);

    // ---- bulk-issue this thread's 16 h-atoms (coalesced: batch k, col tid)
    u64t q[16];
#pragma unroll
    for (int k = 0; k < 16; ++k) q[k] = ld_llc_u64(hr + k * 256 + tid);

    // ---- x @ W while atoms fly (cached loads; independent of q) ----
    f32x4 acc0 = {b0, b0, b0, b0};
    f32x4 acc1 = {b1, b1, b1, b1};
    const __hip_bfloat16* xrow =
        xb + ((size_t)t * BB + grp * GB + l16) * II;
#pragma unroll
    for (int ks = 0; ks < II / 32; ++ks) {
      bf16x8 a = *(const bf16x8*)(xrow + ks * 32 + quad * 8);
      acc0 = __builtin_amdgcn_mfma_f32_16x16x32_bf16(a, wf0[ks], acc0, 0, 0, 0);
      acc1 = __builtin_amdgcn_mfma_f32_16x16x32_bf16(a, wf1[ks], acc1, 0, 0, 0);
    }

    // ---- ONE combined tag check; predicated re-poll of stale atoms only
    for (;;) {
      unsigned bad = 0;
#pragma unroll
      for (int k = 0; k < 16; ++k) bad |= ((unsigned)(q[k] >> 32) ^ ewant);
      if (bad == 0) break;
#pragma unroll
      for (int k = 0; k < 16; ++k)
        if ((unsigned)(q[k] >> 32) != ewant)
          q[k] = ld_llc_u64(hr + k * 256 + tid);
    }

    // ---- scatter h payloads to LDS: thread owns cols (2*tid,2*tid+1) of
    // every batch row ----
#pragma unroll
    for (int k = 0; k < 16; ++k)
      *(unsigned*)(&hL[k][2 * tid]) = (unsigned)q[k];
    __syncthreads();   // SYNC#1: hL complete

    // ---- h @ U: A-frag from LDS, B-frag from registers ----
#pragma unroll
    for (int ks = 0; ks < HH / 32; ++ks) {
      bf16x8 a = *(const bf16x8*)(&hL[l16][ks * 32 + quad * 8]);
      acc0 = __builtin_amdgcn_mfma_f32_16x16x32_bf16(a, uf0[ks], acc0, 0, 0, 0);
      acc1 = __builtin_amdgcn_mfma_f32_16x16x32_bf16(a, uf1[ks], acc1, 0, 0, 0);
    }

    // D layout (verified m89): row = quad*4 + r (batch-local), col = lane's c
#pragma unroll
    for (int r = 0; r < 4; ++r) {
      gate[quad * 4 + r][c0i] = acc0[r];
      gate[quad * 4 + r][c1i] = acc1[r];
    }
    __syncthreads();   // SYNC#2: gates complete

    // ---- elementwise: 2 cells per thread ----
    float hv[2];
#pragma unroll
    for (int s = 0; s < 2; ++s) {
      int j = ej + s;
      float& cst = s ? cs1 : cs0;
      float xi = gate[eb][j];          // i-gate: local col 0*32+j
      float xf = gate[eb][32 + j];     // f
      float xg = gate[eb][64 + j];     // g
      float xo = gate[eb][96 + j];     // o
      float it = 1.f / (1.f + __expf(-xi));
      float ft = 1.f / (1.f + __expf(-xf));
      float gx = fminf(fmaxf(xg, -15.f), 15.f);
      float eg = __expf(2.f * gx);
      float gt = (eg - 1.f) / (eg + 1.f);
      float ot = 1.f / (1.f + __expf(-xo));
      cst = ft * cst + it * gt;
      float cc = fminf(fmaxf(cst, -15.f), 15.f);
      float ec = __expf(2.f * cc);
      float th = (ec - 1.f) / (ec + 1.f);
      hv[s] = ot * th;
    }

    // publish FIRST (critical path): tag<<32 | 2xbf16, one atom
    union { __hip_bfloat16 h2[2]; unsigned u; } hp;
    hp.h2[0] = __float2bfloat16(hv[0]);
    hp.h2[1] = __float2bfloat16(hv[1]);
    st_llc_u64(hw + eb * 256 + w16 * 16 + (ej >> 1),
               ((u64t)epub << 32) | (u64t)hp.u);

    // outputs
    int bglob = grp * GB + eb;
    int hglob = n0 + ej;
    *(float2*)(out + ((size_t)bglob * SS + t) * HH + hglob) =
        make_float2(hv[0], hv[1]);
    if (t == SS - 1) {
      size_t base = (size_t)BB * SS * HH;
      *(float2*)(out + base + (size_t)bglob * HH + hglob) =
          make_float2(hv[0], hv[1]);                        // h_f
      *(float2*)(out + base + (size_t)BB * HH + (size_t)bglob * HH + hglob) =
          make_float2(cs0, cs1);                            // c_f
    }
  }
}

extern "C" void kernel_launch(void* const* d_in, const int* in_sizes, int n_in,
                              void* d_out, int out_size, void* d_ws, size_t ws_size,
                              hipStream_t stream) {
  const float* x = (const float*)d_in[0];     // [64,512,256]
  const float* W = (const float*)d_in[1];     // [256,2048]
  const float* U = (const float*)d_in[2];     // [512,2048]
  const float* bias = (const float*)d_in[3];  // [2048]
  float* out = (float*)d_out;

  char* ws = (char*)d_ws;
  u64t* hpub = (u64t*)ws;                                   // 256 KB
  __hip_bfloat16* Wt = (__hip_bfloat16*)(ws + 256 * 1024);  // 1 MB
  __hip_bfloat16* xb = (__hip_bfloat16*)(ws + 256 * 1024 + G4 * II * 2);

  // zero hpub: tag 0 == epoch of h(-1), payload 0 == h(-1)=0
  hipMemsetAsync(d_ws, 0, 256 * 1024, stream);
  convert_x_kernel<<<BB * SS, II, 0, stream>>>(x, xb);
  transpose_w_kernel<<<128, 256, 0, stream>>>(W, Wt);
  lstm_step<<<NGRP * NWPG, 256, 0, stream>>>(U, bias, xb, Wt, hpub, out);
}